// Round 2
// baseline (546.192 us; speedup 1.0000x reference)
//
#include <hip/hip_runtime.h>
#include <hip/hip_bf16.h>

#define DEVINL __device__ __forceinline__

typedef __attribute__((ext_vector_type(8))) short bf16x8;
typedef __attribute__((ext_vector_type(4))) float f32x4;

static constexpr int Bb = 4, Ss = 2048, Dd = 1024, Hh = 16, DHh = 64;

DEVINL unsigned short f2bf(float f) {
  union { float f; unsigned int u; } a; a.f = f;
  unsigned int u = a.u;
  return (unsigned short)((u + 0x7fffu + ((u >> 16) & 1u)) >> 16);
}

DEVINL void gload16(const void* g, void* l) {
  __builtin_amdgcn_global_load_lds((const __attribute__((address_space(1))) void*)g,
                                   (__attribute__((address_space(3))) void*)l, 16, 0, 0);
}

// ---------------- f32 -> bf16 conversion ----------------
__global__ void cvt_f32_bf16(const float4* __restrict__ src, ushort* __restrict__ dst, int n4) {
  int i = blockIdx.x * blockDim.x + threadIdx.x;
  int stride = gridDim.x * blockDim.x;
  for (; i < n4; i += stride) {
    float4 v = src[i];
    ushort4 o;
    o.x = f2bf(v.x); o.y = f2bf(v.y); o.z = f2bf(v.z); o.w = f2bf(v.w);
    *reinterpret_cast<ushort4*>(dst + (size_t)i * 4) = o;
  }
}

// ---------------- GEMM: C[M,N] = A[M,K] * B[N,K]^T + bias ----------------
// 128x128 tile, BK=32, 4 waves (2x2), each wave 64x64 via 4x4 16x16x32 MFMA frags.
template<int OUT_BF16>
__global__ __launch_bounds__(256)
void gemm_bt(const ushort* __restrict__ A, const ushort* __restrict__ Bm,
             const float* __restrict__ bias, void* __restrict__ Cout,
             int M, int N, int K) {
  __shared__ short lA[128 * 32];
  __shared__ short lB[128 * 32];
  const int tid = threadIdx.x;
  const int lane = tid & 63;
  const int wid = tid >> 6;
  const int wm = wid >> 1, wn = wid & 1;
  const int row0 = blockIdx.x * 128, col0 = blockIdx.y * 128;
  const int lr = lane & 15, lk8 = (lane >> 4) * 8;

  f32x4 acc[4][4];
#pragma unroll
  for (int i = 0; i < 4; i++)
#pragma unroll
    for (int j = 0; j < 4; j++) acc[i][j] = (f32x4){0.f, 0.f, 0.f, 0.f};

  const int c0 = tid, c1 = tid + 256;
  const int r0s = c0 >> 2, k0s = c0 & 3;
  const int r1s = c1 >> 2, k1s = c1 & 3;

  for (int kk = 0; kk < K; kk += 32) {
    __syncthreads();  // previous iteration's reads complete
    gload16(A + (size_t)(row0 + r0s) * K + kk + k0s * 8, lA + c0 * 8);
    gload16(A + (size_t)(row0 + r1s) * K + kk + k1s * 8, lA + c1 * 8);
    gload16(Bm + (size_t)(col0 + r0s) * K + kk + k0s * 8, lB + c0 * 8);
    gload16(Bm + (size_t)(col0 + r1s) * K + kk + k1s * 8, lB + c1 * 8);
    __syncthreads();  // loads landed (compiler drains vmcnt before barrier)

    bf16x8 af[4], bfr[4];
#pragma unroll
    for (int i = 0; i < 4; i++)
      af[i] = *reinterpret_cast<const bf16x8*>(&lA[(wm * 64 + i * 16 + lr) * 32 + lk8]);
#pragma unroll
    for (int j = 0; j < 4; j++)
      bfr[j] = *reinterpret_cast<const bf16x8*>(&lB[(wn * 64 + j * 16 + lr) * 32 + lk8]);
#pragma unroll
    for (int i = 0; i < 4; i++)
#pragma unroll
      for (int j = 0; j < 4; j++)
        acc[i][j] = __builtin_amdgcn_mfma_f32_16x16x32_bf16(af[i], bfr[j], acc[i][j], 0, 0, 0);
  }

  // epilogue: C/D layout col = lane&15, row = (lane>>4)*4 + reg
#pragma unroll
  for (int j = 0; j < 4; j++) {
    const int c = col0 + wn * 64 + j * 16 + lr;
    const float bv = bias[c];
#pragma unroll
    for (int i = 0; i < 4; i++) {
      const int rbase = row0 + wm * 64 + i * 16 + (lane >> 4) * 4;
#pragma unroll
      for (int t = 0; t < 4; t++) {
        float v = acc[i][j][t] + bv;
        if (OUT_BF16)
          reinterpret_cast<ushort*>(Cout)[(size_t)(rbase + t) * N + c] = f2bf(v);
        else
          reinterpret_cast<float*>(Cout)[(size_t)(rbase + t) * N + c] = v;
      }
    }
  }
}

// ---------------- flash attention with multiplicative bool mask ----------------
// grid (S/64, H, B), 256 threads = 4 waves; wave w owns q-rows [q0+16w, q0+16w+16).
// KV tiles of 64. K staged [64][72] (padded), V staged transposed Vt[d][k] [64][72].
// Multiplicative mask: s = (q.k/8) * m, ALL entries participate in softmax.
// mask arrives as int32 (harness canonicalizes bool -> int32).
__global__ __launch_bounds__(256)
void attn_fwd(const ushort* __restrict__ qm, const ushort* __restrict__ km,
              const ushort* __restrict__ vm, const int* __restrict__ mask,
              ushort* __restrict__ ctx) {
  const int qt = blockIdx.x, h = blockIdx.y, b = blockIdx.z;
  const int tid = threadIdx.x, lane = tid & 63, wid = tid >> 6;
  const int q0 = qt * 64;
  const int lr = lane & 15, lg = lane >> 4, lk8 = (lane >> 4) * 8;

  __shared__ short lK[64 * 72];
  __shared__ short lV[64 * 72];      // transposed: lV[d][k], row stride 72
  __shared__ short lP[4][16 * 72];   // per-wave P scratch

  const size_t hb = (size_t)b * Ss * Dd + (size_t)h * DHh;

  // Q fragments held in registers for the whole kernel (A-operand layout:
  // lane holds Q[q0+16w+(lane&15)][(lane>>4)*8 + 32*s .. +8])
  bf16x8 qf[2];
  {
    const ushort* gq = qm + hb + (size_t)(q0 + wid * 16 + lr) * Dd;
    qf[0] = *reinterpret_cast<const bf16x8*>(gq + lk8);
    qf[1] = *reinterpret_cast<const bf16x8*>(gq + 32 + lk8);
  }

  f32x4 oacc[4];
#pragma unroll
  for (int j = 0; j < 4; j++) oacc[j] = (f32x4){0.f, 0.f, 0.f, 0.f};
  float mrun[4], lrun[4];
#pragma unroll
  for (int r = 0; r < 4; r++) { mrun[r] = -1e30f; lrun[r] = 0.f; }

  const int sr = tid >> 2, sseg = tid & 3;  // staging: 4 threads per row, 16 elems each

  for (int t = 0; t < Ss / 64; ++t) {
    const int kk0 = t * 64;
    __syncthreads();
    {
      const ushort* gk = km + hb + (size_t)(kk0 + sr) * Dd + sseg * 16;
      bf16x8 x0 = *reinterpret_cast<const bf16x8*>(gk);
      bf16x8 x1 = *reinterpret_cast<const bf16x8*>(gk + 8);
      *reinterpret_cast<bf16x8*>(&lK[sr * 72 + sseg * 16]) = x0;
      *reinterpret_cast<bf16x8*>(&lK[sr * 72 + sseg * 16 + 8]) = x1;
      const ushort* gv = vm + hb + (size_t)(kk0 + sr) * Dd + sseg * 16;
      bf16x8 y0 = *reinterpret_cast<const bf16x8*>(gv);
      bf16x8 y1 = *reinterpret_cast<const bf16x8*>(gv + 8);
#pragma unroll
      for (int j2 = 0; j2 < 8; j2++) lV[(sseg * 16 + j2) * 72 + sr] = y0[j2];
#pragma unroll
      for (int j2 = 0; j2 < 8; j2++) lV[(sseg * 16 + 8 + j2) * 72 + sr] = y1[j2];
    }
    __syncthreads();

    // scores S[16][64]: 4 col-frags, K-dim = DH = 64 -> 2 MFMAs each
    f32x4 sc[4];
#pragma unroll
    for (int f = 0; f < 4; ++f) {
      bf16x8 kb0 = *reinterpret_cast<const bf16x8*>(&lK[(f * 16 + lr) * 72 + lk8]);
      bf16x8 kb1 = *reinterpret_cast<const bf16x8*>(&lK[(f * 16 + lr) * 72 + 32 + lk8]);
      f32x4 z = (f32x4){0.f, 0.f, 0.f, 0.f};
      z = __builtin_amdgcn_mfma_f32_16x16x32_bf16(qf[0], kb0, z, 0, 0, 0);
      z = __builtin_amdgcn_mfma_f32_16x16x32_bf16(qf[1], kb1, z, 0, 0, 0);
      sc[f] = z;
    }

    // multiplicative mask + scale + online softmax (rows = (lane>>4)*4 + r)
    float pv[4][4];   // [colfrag][reg] : masked score, then p
    float alpha[4];
#pragma unroll
    for (int r = 0; r < 4; ++r) {
      const int qrow = q0 + wid * 16 + lg * 4 + r;
      const int* mp = mask + (size_t)b * Ss * Ss + (size_t)qrow * Ss + kk0 + lr;
      float rmax = -1e30f;
#pragma unroll
      for (int f = 0; f < 4; ++f) {
        float sv = sc[f][r] * 0.125f * (float)mp[f * 16];
        pv[f][r] = sv;
        rmax = fmaxf(rmax, sv);
      }
#pragma unroll
      for (int off = 1; off < 16; off <<= 1) rmax = fmaxf(rmax, __shfl_xor(rmax, off, 64));
      const float mn = fmaxf(mrun[r], rmax);
      alpha[r] = __expf(mrun[r] - mn);
      mrun[r] = mn;
      float rs = 0.f;
#pragma unroll
      for (int f = 0; f < 4; ++f) {
        float p = __expf(pv[f][r] - mn);
        pv[f][r] = p;
        rs += p;
      }
#pragma unroll
      for (int off = 1; off < 16; off <<= 1) rs += __shfl_xor(rs, off, 64);
      lrun[r] = lrun[r] * alpha[r] + rs;
    }
#pragma unroll
    for (int j = 0; j < 4; j++)
#pragma unroll
      for (int r = 0; r < 4; r++) oacc[j][r] *= alpha[r];

    // P -> per-wave LDS (acc layout) -> A-operand fragments
    short* pw = &lP[wid][0];
#pragma unroll
    for (int r = 0; r < 4; r++)
#pragma unroll
      for (int f = 0; f < 4; f++)
        pw[(lg * 4 + r) * 72 + f * 16 + lr] = (short)f2bf(pv[f][r]);

    __builtin_amdgcn_wave_barrier();  // compiler fence: DS write->read same wave

    bf16x8 pa0 = *reinterpret_cast<const bf16x8*>(&pw[lr * 72 + lk8]);
    bf16x8 pa1 = *reinterpret_cast<const bf16x8*>(&pw[lr * 72 + 32 + lk8]);

    // O[16][64] += P[16][64] * V[64][64]; B-operand from transposed lV
#pragma unroll
    for (int j = 0; j < 4; ++j) {
      bf16x8 vb0 = *reinterpret_cast<const bf16x8*>(&lV[(j * 16 + lr) * 72 + lk8]);
      bf16x8 vb1 = *reinterpret_cast<const bf16x8*>(&lV[(j * 16 + lr) * 72 + 32 + lk8]);
      oacc[j] = __builtin_amdgcn_mfma_f32_16x16x32_bf16(pa0, vb0, oacc[j], 0, 0, 0);
      oacc[j] = __builtin_amdgcn_mfma_f32_16x16x32_bf16(pa1, vb1, oacc[j], 0, 0, 0);
    }
  }

  // epilogue: O /= l, write context bf16 into [B,S,D] (head-merged)
  float invl[4];
#pragma unroll
  for (int r = 0; r < 4; r++) invl[r] = 1.0f / lrun[r];
#pragma unroll
  for (int j = 0; j < 4; j++)
#pragma unroll
    for (int r = 0; r < 4; r++) {
      const int row = q0 + wid * 16 + lg * 4 + r;
      const int col = h * DHh + j * 16 + lr;
      ctx[((size_t)b * Ss + row) * Dd + col] = (short)f2bf(oacc[j][r] * invl[r]);
    }
}

// ---------------- launch ----------------
extern "C" void kernel_launch(void* const* d_in, const int* in_sizes, int n_in,
                              void* d_out, int out_size, void* d_ws, size_t ws_size,
                              hipStream_t stream) {
  const float* query = (const float*)d_in[0];
  const int* mask = (const int*)d_in[1];  // bool canonicalized to int32 by harness
  const float* Wq = (const float*)d_in[2];
  const float* bq = (const float*)d_in[3];
  const float* Wk = (const float*)d_in[4];
  const float* bk = (const float*)d_in[5];
  const float* Wv = (const float*)d_in[6];
  const float* bv = (const float*)d_in[7];
  const float* Wo = (const float*)d_in[8];
  const float* bo = (const float*)d_in[9];
  float* out = (float*)d_out;

  ushort* ws = (ushort*)d_ws;
  const size_t MD = (size_t)8192 * 1024;
  ushort* xB  = ws;            // query bf16
  ushort* qB  = ws + MD;
  ushort* kB  = ws + 2 * MD;
  ushort* vB  = ws + 3 * MD;
  ushort* ctx = ws + 4 * MD;
  ushort* wqB = ws + 5 * MD;
  ushort* wkB = wqB + (size_t)1024 * 1024;
  ushort* wvB = wkB + (size_t)1024 * 1024;
  ushort* woB = wvB + (size_t)1024 * 1024;

  dim3 blk(256);
  cvt_f32_bf16<<<2048, blk, 0, stream>>>((const float4*)query, xB, (int)(MD / 4));
  cvt_f32_bf16<<<512, blk, 0, stream>>>((const float4*)Wq, wqB, 1024 * 1024 / 4);
  cvt_f32_bf16<<<512, blk, 0, stream>>>((const float4*)Wk, wkB, 1024 * 1024 / 4);
  cvt_f32_bf16<<<512, blk, 0, stream>>>((const float4*)Wv, wvB, 1024 * 1024 / 4);
  cvt_f32_bf16<<<512, blk, 0, stream>>>((const float4*)Wo, woB, 1024 * 1024 / 4);

  dim3 g1(64, 8);
  gemm_bt<1><<<g1, blk, 0, stream>>>(xB, wqB, bq, qB, 8192, 1024, 1024);
  gemm_bt<1><<<g1, blk, 0, stream>>>(xB, wkB, bk, kB, 8192, 1024, 1024);
  gemm_bt<1><<<g1, blk, 0, stream>>>(xB, wvB, bv, vB, 8192, 1024, 1024);

  dim3 ga(32, 16, 4);
  attn_fwd<<<ga, blk, 0, stream>>>(qB, kB, vB, mask, ctx);

  gemm_bt<0><<<g1, blk, 0, stream>>>(ctx, woB, bo, out, 8192, 1024, 1024);
}

// Round 3
// 453.226 us; speedup vs baseline: 1.2051x; 1.2051x over previous
//
#include <hip/hip_runtime.h>
#include <hip/hip_bf16.h>

#define DEVINL __device__ __forceinline__

typedef __attribute__((ext_vector_type(8))) short bf16x8;
typedef __attribute__((ext_vector_type(4))) float f32x4;

static constexpr int Bb = 4, Ss = 2048, Dd = 1024, Hh = 16, DHh = 64;
// Q prescale: 0.125 (1/sqrt(DH)) * log2(e) so softmax runs in exp2 domain
#define QPRESCALE 0.18033688f
#define DEFER_THR 11.5f   /* log2 units ~= e^8 */

DEVINL unsigned short f2bf(float f) {
  union { float f; unsigned int u; } a; a.f = f;
  unsigned int u = a.u;
  return (unsigned short)((u + 0x7fffu + ((u >> 16) & 1u)) >> 16);
}

DEVINL float fexp2(float x) {
#if __has_builtin(__builtin_amdgcn_exp2f)
  return __builtin_amdgcn_exp2f(x);
#else
  return __builtin_exp2f(x);
#endif
}

DEVINL void gload16(const void* g, void* l) {
  __builtin_amdgcn_global_load_lds((const __attribute__((address_space(1))) void*)g,
                                   (__attribute__((address_space(3))) void*)l, 16, 0, 0);
}

// ---------------- f32 -> bf16 conversion ----------------
__global__ void cvt_f32_bf16(const float4* __restrict__ src, ushort* __restrict__ dst, int n4) {
  int i = blockIdx.x * blockDim.x + threadIdx.x;
  int stride = gridDim.x * blockDim.x;
  for (; i < n4; i += stride) {
    float4 v = src[i];
    ushort4 o;
    o.x = f2bf(v.x); o.y = f2bf(v.y); o.z = f2bf(v.z); o.w = f2bf(v.w);
    *reinterpret_cast<ushort4*>(dst + (size_t)i * 4) = o;
  }
}

// ---------------- concat biases (q,k,v) into one 3072 vector ----------------
__global__ void bias_cat(const float* __restrict__ bq, const float* __restrict__ bk,
                         const float* __restrict__ bv, float* __restrict__ bcat) {
  int i = blockIdx.x * blockDim.x + threadIdx.x;
  if (i < 1024) bcat[i] = bq[i];
  else if (i < 2048) bcat[i] = bk[i - 1024];
  else if (i < 3072) bcat[i] = bv[i - 2048];
}

// ---------------- mask int32 -> transposed bitmask [B][S/64][S] uint64 ----------------
__global__ void mask_bits(const int* __restrict__ mask, unsigned long long* __restrict__ bm) {
  const int tid = threadIdx.x, lane = tid & 63;
  const int gw = blockIdx.x * 4 + (tid >> 6);      // one wave per 64-chunk
  const int b = gw >> 16;                          // 2048*32 = 65536 chunks per batch
  const int rem = gw & 65535;
  const int s = rem >> 5, ch = rem & 31;
  int m = mask[((size_t)b * Ss + s) * Ss + ch * 64 + lane];
  unsigned long long bits = __ballot(m != 0);
  if (lane == 0) bm[((size_t)b * 32 + ch) * Ss + s] = bits;
}

// ---------------- GEMM: C[M,N] = A[M,K] * B[N,K]^T + bias ----------------
// 128x128 tile, BK=32, 4 waves (2x2). QSCALE: scale cols<1024 by QPRESCALE.
template<int OUT_BF16, int QSCALE>
__global__ __launch_bounds__(256)
void gemm_bt(const ushort* __restrict__ A, const ushort* __restrict__ Bm,
             const float* __restrict__ bias, void* __restrict__ Cout,
             int M, int N, int K) {
  __shared__ short lA[128 * 32];
  __shared__ short lB[128 * 32];
  const int tid = threadIdx.x;
  const int lane = tid & 63;
  const int wid = tid >> 6;
  const int wm = wid >> 1, wn = wid & 1;
  const int row0 = blockIdx.x * 128, col0 = blockIdx.y * 128;
  const int lr = lane & 15, lk8 = (lane >> 4) * 8;

  f32x4 acc[4][4];
#pragma unroll
  for (int i = 0; i < 4; i++)
#pragma unroll
    for (int j = 0; j < 4; j++) acc[i][j] = (f32x4){0.f, 0.f, 0.f, 0.f};

  const int c0 = tid, c1 = tid + 256;
  const int r0s = c0 >> 2, k0s = c0 & 3;
  const int r1s = c1 >> 2, k1s = c1 & 3;

  for (int kk = 0; kk < K; kk += 32) {
    __syncthreads();
    gload16(A + (size_t)(row0 + r0s) * K + kk + k0s * 8, lA + c0 * 8);
    gload16(A + (size_t)(row0 + r1s) * K + kk + k1s * 8, lA + c1 * 8);
    gload16(Bm + (size_t)(col0 + r0s) * K + kk + k0s * 8, lB + c0 * 8);
    gload16(Bm + (size_t)(col0 + r1s) * K + kk + k1s * 8, lB + c1 * 8);
    __syncthreads();

    bf16x8 af[4], bfr[4];
#pragma unroll
    for (int i = 0; i < 4; i++)
      af[i] = *reinterpret_cast<const bf16x8*>(&lA[(wm * 64 + i * 16 + lr) * 32 + lk8]);
#pragma unroll
    for (int j = 0; j < 4; j++)
      bfr[j] = *reinterpret_cast<const bf16x8*>(&lB[(wn * 64 + j * 16 + lr) * 32 + lk8]);
#pragma unroll
    for (int i = 0; i < 4; i++)
#pragma unroll
      for (int j = 0; j < 4; j++)
        acc[i][j] = __builtin_amdgcn_mfma_f32_16x16x32_bf16(af[i], bfr[j], acc[i][j], 0, 0, 0);
  }

#pragma unroll
  for (int j = 0; j < 4; j++) {
    const int c = col0 + wn * 64 + j * 16 + lr;
    const float bv = bias[c];
    const float qs = (QSCALE && c < 1024) ? QPRESCALE : 1.0f;
#pragma unroll
    for (int i = 0; i < 4; i++) {
      const int rbase = row0 + wm * 64 + i * 16 + (lane >> 4) * 4;
#pragma unroll
      for (int t = 0; t < 4; t++) {
        float v = (acc[i][j][t] + bv) * qs;
        if (OUT_BF16)
          reinterpret_cast<ushort*>(Cout)[(size_t)(rbase + t) * N + c] = f2bf(v);
        else
          reinterpret_cast<float*>(Cout)[(size_t)(rbase + t) * N + c] = v;
      }
    }
  }
}

// ---------------- flash attention, multiplicative bitmask, exp2 domain ----------------
// grid (S/64, H, B), 4 waves. K via global_load_lds w/ pre-swizzled source;
// V reg-staged transposed w/ combined XOR swizzle; P per-wave swizzled;
// mask from packed transposed bitmask (512B/tile, broadcast reads).
__global__ __launch_bounds__(256)
void attn_fwd(const ushort* __restrict__ qkv, const unsigned long long* __restrict__ bmask,
              ushort* __restrict__ ctx) {
  const int qt = blockIdx.x, h = blockIdx.y, b = blockIdx.z;
  const int tid = threadIdx.x, lane = tid & 63, wid = tid >> 6;
  const int q0 = qt * 64;
  const int lr = lane & 15, lg = lane >> 4;
  const int RS = 3072;

  __shared__ short lK[64 * 64];
  __shared__ short lV[64 * 64];
  __shared__ short lP[4][16 * 64];
  __shared__ unsigned long long lM[64];

  const size_t rowb = (size_t)b * Ss;

  // Q fragments (already scaled by QPRESCALE in the QKV GEMM epilogue)
  bf16x8 qf[2];
  {
    const ushort* gq = qkv + (rowb + q0 + wid * 16 + lr) * RS + h * 64;
    qf[0] = *reinterpret_cast<const bf16x8*>(gq + lg * 8);
    qf[1] = *reinterpret_cast<const bf16x8*>(gq + 32 + lg * 8);
  }

  f32x4 oacc[4];
#pragma unroll
  for (int j = 0; j < 4; j++) oacc[j] = (f32x4){0.f, 0.f, 0.f, 0.f};
  float mrun[4], lp[4];
#pragma unroll
  for (int r = 0; r < 4; r++) { mrun[r] = -1e30f; lp[r] = 0.f; }

  const int sr = tid >> 2, sseg = tid & 3;  // V staging: k-row sr, d-chunk sseg

  for (int t = 0; t < Ss / 64; ++t) {
    __syncthreads();
    // ---- K: global_load_lds, source pre-swizzled so LDS slot (row, s) holds
    //      global 16B-chunk s ^ (row&7)  (linear LDS dest, rule 21)
    {
      const ushort* Kg = qkv + (rowb + t * 64) * RS + 1024 + h * 64;
      int c = tid, row = c >> 3, c7 = c & 7;
      gload16(Kg + (size_t)row * RS + ((c7 ^ (row & 7)) * 8), ((char*)lK) + c * 16);
      c = tid + 256; row = c >> 3; c7 = c & 7;
      gload16(Kg + (size_t)row * RS + ((c7 ^ (row & 7)) * 8), ((char*)lK) + c * 16);
    }
    // ---- V: reg-staged transpose lV[d][k], swizzle k ^= ((d&7)^((d>>4)&3))<<3
    {
      const ushort* gv = qkv + (rowb + t * 64 + sr) * RS + 2048 + h * 64 + sseg * 16;
      bf16x8 y0 = *reinterpret_cast<const bf16x8*>(gv);
      bf16x8 y1 = *reinterpret_cast<const bf16x8*>(gv + 8);
#pragma unroll
      for (int j2 = 0; j2 < 8; j2++) {
        int d = sseg * 16 + j2;
        lV[d * 64 + (sr ^ ((j2 ^ sseg) << 3))] = y0[j2];
      }
#pragma unroll
      for (int j2 = 0; j2 < 8; j2++) {
        int d = sseg * 16 + 8 + j2;
        lV[d * 64 + (sr ^ ((j2 ^ sseg) << 3))] = y1[j2];
      }
    }
    // ---- mask bits for this k-chunk (transposed layout: 64 consecutive u64)
    if (tid < 64) lM[tid] = bmask[((size_t)b * 32 + t) * Ss + q0 + tid];
    __syncthreads();

    // ---- QK^T: S[16 q][64 k] per wave
    f32x4 sc[4];
    __builtin_amdgcn_s_setprio(1);
#pragma unroll
    for (int f = 0; f < 4; ++f) {
      const int row = f * 16 + lr;
      const int s0 = (lg ^ (lr & 7)) * 8;
      bf16x8 kb0 = *reinterpret_cast<const bf16x8*>(&lK[row * 64 + s0]);
      bf16x8 kb1 = *reinterpret_cast<const bf16x8*>(&lK[row * 64 + (s0 ^ 32)]);
      f32x4 z = (f32x4){0.f, 0.f, 0.f, 0.f};
      z = __builtin_amdgcn_mfma_f32_16x16x32_bf16(qf[0], kb0, z, 0, 0, 0);
      z = __builtin_amdgcn_mfma_f32_16x16x32_bf16(qf[1], kb1, z, 0, 0, 0);
      sc[f] = z;
    }
    __builtin_amdgcn_s_setprio(0);

    // ---- multiplicative mask + defer-max online softmax (log2 domain)
    float pv[4][4];
    float tmax = -1e30f;
#pragma unroll
    for (int r = 0; r < 4; ++r) {
      const unsigned long long m64 = lM[wid * 16 + lg * 4 + r];
      const unsigned wlo = (unsigned)m64, whi = (unsigned)(m64 >> 32);
#pragma unroll
      for (int f = 0; f < 4; ++f) {
        const unsigned w = (f & 2) ? whi : wlo;
        const int sh = ((f & 1) << 4) + lr;
        float sv = ((w >> sh) & 1u) ? sc[f][r] : 0.0f;
        pv[f][r] = sv;
        tmax = fmaxf(tmax, sv);
      }
    }
#pragma unroll
    for (int off = 1; off < 64; off <<= 1) tmax = fmaxf(tmax, __shfl_xor(tmax, off, 64));
    const float minm = fminf(fminf(mrun[0], mrun[1]), fminf(mrun[2], mrun[3]));
    if (!__all(tmax <= minm + DEFER_THR)) {
      // rescale path (rare: first tile / large max growth)
#pragma unroll
      for (int r = 0; r < 4; ++r) {
        float rm = fmaxf(fmaxf(pv[0][r], pv[1][r]), fmaxf(pv[2][r], pv[3][r]));
#pragma unroll
        for (int off = 1; off < 16; off <<= 1) rm = fmaxf(rm, __shfl_xor(rm, off, 64));
        const float mn = fmaxf(mrun[r], rm);
        const float al = fexp2(mrun[r] - mn);
        mrun[r] = mn;
        lp[r] *= al;
#pragma unroll
        for (int j = 0; j < 4; j++) oacc[j][r] *= al;
      }
    }
#pragma unroll
    for (int r = 0; r < 4; ++r)
#pragma unroll
      for (int f = 0; f < 4; ++f) {
        float p = fexp2(pv[f][r] - mrun[r]);
        pv[f][r] = p;
        lp[r] += p;   // per-lane partial row sum; cross-lane reduce deferred
      }

    // ---- P -> per-wave LDS (swizzled: kbyte ^= (q>>2)<<5)
    short* pw = &lP[wid][0];
#pragma unroll
    for (int r = 0; r < 4; r++) {
      const int q = lg * 4 + r;
      const int swp = (q >> 2) << 4;  // shorts
#pragma unroll
      for (int f = 0; f < 4; f++)
        pw[q * 64 + ((f * 16 + lr) ^ swp)] = (short)f2bf(pv[f][r]);
    }
    __builtin_amdgcn_wave_barrier();
    {
      const int swp = (lr >> 2) << 4;
      bf16x8 pa0 = *reinterpret_cast<const bf16x8*>(&pw[lr * 64 + ((lg * 8) ^ swp)]);
      bf16x8 pa1 = *reinterpret_cast<const bf16x8*>(&pw[lr * 64 + ((32 + lg * 8) ^ swp)]);
      __builtin_amdgcn_s_setprio(1);
#pragma unroll
      for (int j = 0; j < 4; ++j) {
        const int d = j * 16 + lr;
        const int sv2 = ((lr & 7) ^ j) << 3;
        bf16x8 vb0 = *reinterpret_cast<const bf16x8*>(&lV[d * 64 + ((lg * 8) ^ sv2)]);
        bf16x8 vb1 = *reinterpret_cast<const bf16x8*>(&lV[d * 64 + ((32 + lg * 8) ^ sv2)]);
        oacc[j] = __builtin_amdgcn_mfma_f32_16x16x32_bf16(pa0, vb0, oacc[j], 0, 0, 0);
        oacc[j] = __builtin_amdgcn_mfma_f32_16x16x32_bf16(pa1, vb1, oacc[j], 0, 0, 0);
      }
      __builtin_amdgcn_s_setprio(0);
    }
    __builtin_amdgcn_wave_barrier();
  }

  // ---- epilogue: deferred row-sum reduce, normalize, write ctx
#pragma unroll
  for (int r = 0; r < 4; ++r) {
#pragma unroll
    for (int off = 1; off < 16; off <<= 1) lp[r] += __shfl_xor(lp[r], off, 64);
  }
  float invl[4];
#pragma unroll
  for (int r = 0; r < 4; r++) invl[r] = 1.0f / lp[r];
#pragma unroll
  for (int j = 0; j < 4; j++)
#pragma unroll
    for (int r = 0; r < 4; r++) {
      const int row = q0 + wid * 16 + lg * 4 + r;
      const int col = h * DHh + j * 16 + lr;
      ctx[(rowb + row) * Dd + col] = (short)f2bf(oacc[j][r] * invl[r]);
    }
}

// ---------------- launch ----------------
extern "C" void kernel_launch(void* const* d_in, const int* in_sizes, int n_in,
                              void* d_out, int out_size, void* d_ws, size_t ws_size,
                              hipStream_t stream) {
  const float* query = (const float*)d_in[0];
  const int* mask = (const int*)d_in[1];
  const float* Wq = (const float*)d_in[2];
  const float* bq = (const float*)d_in[3];
  const float* Wk = (const float*)d_in[4];
  const float* bk = (const float*)d_in[5];
  const float* Wv = (const float*)d_in[6];
  const float* bv = (const float*)d_in[7];
  const float* Wo = (const float*)d_in[8];
  const float* bo = (const float*)d_in[9];
  float* out = (float*)d_out;

  ushort* ws = (ushort*)d_ws;
  const size_t SZ_X = (size_t)8192 * 1024;       // 8388608
  ushort* xB   = ws;                              // [8192][1024] bf16; later reused as ctx
  ushort* ctx  = ws;                              // overlay (xB dead after QKV gemm)
  ushort* qkvB = ws + SZ_X;                       // [8192][3072] bf16
  ushort* wcat = qkvB + (size_t)8192 * 3072;      // [3072][1024] bf16 (Wq|Wk|Wv)
  ushort* woB  = wcat + (size_t)3072 * 1024;      // [1024][1024] bf16
  float*  bcat = (float*)(woB + (size_t)1024 * 1024);          // 3072 f32
  unsigned long long* bmask = (unsigned long long*)((char*)bcat + 16384); // 2MB

  dim3 blk(256);
  cvt_f32_bf16<<<2048, blk, 0, stream>>>((const float4*)query, xB, (int)(SZ_X / 4));
  cvt_f32_bf16<<<512, blk, 0, stream>>>((const float4*)Wq, wcat, 1024 * 1024 / 4);
  cvt_f32_bf16<<<512, blk, 0, stream>>>((const float4*)Wk, wcat + 1048576, 1024 * 1024 / 4);
  cvt_f32_bf16<<<512, blk, 0, stream>>>((const float4*)Wv, wcat + 2097152, 1024 * 1024 / 4);
  cvt_f32_bf16<<<512, blk, 0, stream>>>((const float4*)Wo, woB, 1024 * 1024 / 4);
  bias_cat<<<12, blk, 0, stream>>>(bq, bk, bv, bcat);
  mask_bits<<<65536, blk, 0, stream>>>(mask, bmask);

  // fused QKV projection: [8192][3072], q-cols pre-scaled by 0.125*log2e
  dim3 gqkv(64, 24);
  gemm_bt<1, 1><<<gqkv, blk, 0, stream>>>(xB, wcat, bcat, qkvB, 8192, 3072, 1024);

  dim3 ga(32, 16, 4);
  attn_fwd<<<ga, blk, 0, stream>>>(qkvB, bmask, ctx);

  dim3 go(64, 8);
  gemm_bt<0, 0><<<go, blk, 0, stream>>>(ctx, woB, bo, out, 8192, 1024, 1024);
}